// Round 2
// baseline (1675.769 us; speedup 1.0000x reference)
//
#include <hip/hip_runtime.h>

typedef unsigned int u32;
typedef __fp16 f16;
typedef __fp16 h2 __attribute__((ext_vector_type(2)));
typedef __fp16 h8 __attribute__((ext_vector_type(8)));
typedef float f32x2v __attribute__((ext_vector_type(2)));
typedef float f32x4v __attribute__((ext_vector_type(4)));
typedef float f32x16v __attribute__((ext_vector_type(16)));
typedef u32 u32x4v __attribute__((ext_vector_type(4)));

static constexpr int BB = 64;     // batch
static constexpr int TT = 1024;   // seq len
static constexpr int HH = 256;    // hidden
static constexpr int GG = 768;    // 3*H
static constexpr size_t GI_BYTES = (size_t)BB * TT * GG * 2;  // f16 gi buffer

__device__ __forceinline__ u32 pk2(float a, float b) {
  h2 r = __builtin_amdgcn_cvt_pkrtz(a, b);
  return __builtin_bit_cast(u32, r);
}
__device__ __forceinline__ float fdot2u(u32 a, u32 b, float c) {
  return __builtin_amdgcn_fdot2(__builtin_bit_cast(h2, a), __builtin_bit_cast(h2, b), c, false);
}
__device__ __forceinline__ float dpp_x1(float x) {  // quad_perm [1,0,3,2]
  return __builtin_bit_cast(float,
      __builtin_amdgcn_mov_dpp(__builtin_bit_cast(int, x), 0xB1, 0xF, 0xF, true));
}
__device__ __forceinline__ float dpp_x2(float x) {  // quad_perm [2,3,0,1]
  return __builtin_bit_cast(float,
      __builtin_amdgcn_mov_dpp(__builtin_bit_cast(int, x), 0x4E, 0xF, 0xF, true));
}
__device__ __forceinline__ float sigf(float x) { return 1.f / (1.f + __expf(-x)); }
__device__ __forceinline__ float tanhf2(float x) {
  float e = __expf(2.f * x);
  return 1.f - 2.f / (e + 1.f);
}

// ---------------------------------------------------------------------------
// Phase 0: prepack W_hh (768x256 fp32) into per-thread f16x2 streams.
// Recur thread j (q=j>>2, kq=j&3) owns rows 4q..4q+3 over k in [64kq,64kq+64).
// Register v of thread j = W[4q + (v>>5)][64kq + 2(v&31) .. +1], packed f16x2.
// Layout Wp[v*768 + j] so init loads are fully coalesced.
// ---------------------------------------------------------------------------
__global__ void prepack_whh(const float* __restrict__ Whh, u32* __restrict__ Wp) {
  int id = blockIdx.x * 256 + threadIdx.x;  // [0, 128*768)
  int v = id / GG;
  int j = id - v * GG;
  int q = j >> 2, kq = j & 3;
  int row = 4 * q + (v >> 5);
  int k0 = 64 * kq + 2 * (v & 31);
  const float* p = Whh + (size_t)row * HH + k0;
  Wp[id] = pk2(p[0], p[1]);
}

// ---------------------------------------------------------------------------
// Phase 1: gi = x @ W_ih^T + b_ih, stored f16.  M=65536, N=768, K=256.
// 256 threads (4 waves, 2x2), block tile 128 rows x (loop over 6 n-tiles of 128).
// A (x) fragments held in registers full-K (128 VGPR), B staged in 64KB LDS
// with XOR swizzle; mfma_f32_32x32x16_f16.
// ---------------------------------------------------------------------------
__device__ __forceinline__ f32x16v zero16() {
  f32x16v z;
#pragma unroll
  for (int i = 0; i < 16; ++i) z[i] = 0.f;
  return z;
}

__global__ __launch_bounds__(256, 2) void gemm_gi(
    const float* __restrict__ x, const float* __restrict__ Wih,
    const float* __restrict__ bih, f16* __restrict__ gi) {
  __shared__ u32 bl[16384];  // 128 rows x 128 dwords (f16x2) = 64KB
  const int tid = threadIdx.x;
  const int lane = tid & 63;
  const int wv = tid >> 6;
  const int wr = wv >> 1, wc = wv & 1;
  const int l31 = lane & 31, lh = lane >> 5;
  const int m0 = blockIdx.x << 7;

  // A fragments: 2 row-frags x 16 k-steps, each 4 f16x2 words per lane
  u32x4v afr[2][16];
#pragma unroll
  for (int fr = 0; fr < 2; ++fr) {
#pragma unroll
    for (int km = 0; km < 16; ++km) {
      int row = m0 + wr * 64 + fr * 32 + l31;
      int k0 = km * 16 + lh * 8;
      const f32x4v* p = (const f32x4v*)(x + (size_t)row * 256 + k0);
      f32x4v u = p[0], v = p[1];
      u32x4v t;
      t.x = pk2(u.x, u.y); t.y = pk2(u.z, u.w);
      t.z = pk2(v.x, v.y); t.w = pk2(v.z, v.w);
      afr[fr][km] = t;
    }
  }

  for (int nt = 0; nt < 6; ++nt) {
    const int n0 = nt << 7;
    // stage B tile: W_ih rows [n0, n0+128) x 256 k, fp32 -> f16x2, XOR swizzle
#pragma unroll
    for (int i = 0; i < 64; ++i) {
      int idx = i * 256 + tid;
      int r = idx >> 7, wd = idx & 127;
      const f32x2v* g = (const f32x2v*)(Wih + (size_t)(n0 + r) * 256 + 2 * wd);
      f32x2v f = *g;
      bl[r * 128 + (wd ^ ((r & 15) << 2))] = pk2(f.x, f.y);
    }
    __syncthreads();

    f32x16v acc00 = zero16(), acc01 = zero16(), acc10 = zero16(), acc11 = zero16();
#pragma unroll
    for (int km = 0; km < 16; ++km) {
      int w0 = km * 8 + lh * 4;
      int rc0 = wc * 64 + l31;
      int rc1 = wc * 64 + 32 + l31;
      u32x4v b0 = *(const u32x4v*)&bl[rc0 * 128 + (w0 ^ ((rc0 & 15) << 2))];
      u32x4v b1 = *(const u32x4v*)&bl[rc1 * 128 + (w0 ^ ((rc1 & 15) << 2))];
      h8 a0h = __builtin_bit_cast(h8, afr[0][km]);
      h8 a1h = __builtin_bit_cast(h8, afr[1][km]);
      h8 b0h = __builtin_bit_cast(h8, b0);
      h8 b1h = __builtin_bit_cast(h8, b1);
      acc00 = __builtin_amdgcn_mfma_f32_32x32x16_f16(a0h, b0h, acc00, 0, 0, 0);
      acc10 = __builtin_amdgcn_mfma_f32_32x32x16_f16(a1h, b0h, acc10, 0, 0, 0);
      acc01 = __builtin_amdgcn_mfma_f32_32x32x16_f16(a0h, b1h, acc01, 0, 0, 0);
      acc11 = __builtin_amdgcn_mfma_f32_32x32x16_f16(a1h, b1h, acc11, 0, 0, 0);
    }

    // epilogue: D col = lane&31, row = (reg&3) + 8*(reg>>2) + 4*(lane>>5)
#define EPI(ACC, FR, FC)                                                      \
    {                                                                         \
      int gc = n0 + wc * 64 + (FC) * 32 + l31;                                \
      float bias = bih[gc];                                                   \
      _Pragma("unroll")                                                       \
      for (int rg = 0; rg < 16; ++rg) {                                       \
        int gr = m0 + wr * 64 + (FR) * 32 + 4 * lh + (rg & 3) + 8 * (rg >> 2);\
        gi[(size_t)gr * 768 + gc] = (f16)(ACC[rg] + bias);                    \
      }                                                                       \
    }
    EPI(acc00, 0, 0) EPI(acc10, 1, 0) EPI(acc01, 0, 1) EPI(acc11, 1, 1)
#undef EPI
    __syncthreads();
  }
}

// ---------------------------------------------------------------------------
// Phase 2: the recurrence. 64 blocks (1/batch), 768 threads (12 waves).
// Thread j: q=j>>2 owns rows 4q..4q+3 over k-quarter kq=j&3 (weights in 128
// VGPRs). h (f16x2) in LDS, 4 padded quarters; 8x ds_read_b128 per thread per
// step; quad DPP reduction leaves thread j owning full gh[j].
// ---------------------------------------------------------------------------
#define DOT4(C, QQ)                                                   \
  a0 = fdot2u(w[(C) * 4 + 0], (QQ).x, a0);                            \
  a0 = fdot2u(w[(C) * 4 + 1], (QQ).y, a0);                            \
  a0 = fdot2u(w[(C) * 4 + 2], (QQ).z, a0);                            \
  a0 = fdot2u(w[(C) * 4 + 3], (QQ).w, a0);                            \
  a1 = fdot2u(w[32 + (C) * 4 + 0], (QQ).x, a1);                       \
  a1 = fdot2u(w[32 + (C) * 4 + 1], (QQ).y, a1);                       \
  a1 = fdot2u(w[32 + (C) * 4 + 2], (QQ).z, a1);                       \
  a1 = fdot2u(w[32 + (C) * 4 + 3], (QQ).w, a1);                       \
  a2 = fdot2u(w[64 + (C) * 4 + 0], (QQ).x, a2);                       \
  a2 = fdot2u(w[64 + (C) * 4 + 1], (QQ).y, a2);                       \
  a2 = fdot2u(w[64 + (C) * 4 + 2], (QQ).z, a2);                       \
  a2 = fdot2u(w[64 + (C) * 4 + 3], (QQ).w, a2);                       \
  a3 = fdot2u(w[96 + (C) * 4 + 0], (QQ).x, a3);                       \
  a3 = fdot2u(w[96 + (C) * 4 + 1], (QQ).y, a3);                       \
  a3 = fdot2u(w[96 + (C) * 4 + 2], (QQ).z, a3);                       \
  a3 = fdot2u(w[96 + (C) * 4 + 3], (QQ).w, a3);

__global__ __launch_bounds__(768) void recur(
    const u32* __restrict__ Wp, const f16* __restrict__ gi,
    const float* __restrict__ states, const float* __restrict__ mask,
    const float* __restrict__ bhh_g, float* __restrict__ out) {
  const int b = blockIdx.x;
  const int j = threadIdx.x;
  const int kq = j & 3;

  __shared__ u32 h16[160];    // 4 quarters of 32 dwords, padded to 40 (bank offset 8)
  __shared__ float sbuf[768];
  __shared__ float gbuf[256];

  u32 w[128];
#pragma unroll
  for (int v = 0; v < 128; ++v) w[v] = Wp[(size_t)v * 768 + j];
  float bhh = bhh_g[j];

  const float* mk = mask + b * TT;
  const f16* gib = gi + (size_t)b * TT * GG;
  float* outb = out + (size_t)b * TT * HH;
  f16* h16h = (f16*)h16;

  float hreg = 0.f;
  if (j < 256) {
    hreg = states[b * HH + j] * mk[0];
    int wd = j >> 1;
    h16h[((wd >> 5) * 40 + (wd & 31)) * 2 + (j & 1)] = (f16)hreg;
  }
  __syncthreads();

  const u32x4v* hq = (const u32x4v*)&h16[kq * 40];

  for (int t = 0; t < TT; ++t) {
    float giv = (float)gib[(size_t)t * GG + j];
    float mt = mk[t];
    float a0 = 0.f, a1 = 0.f, a2 = 0.f, a3 = 0.f;
    u32x4v q0 = hq[0], q1 = hq[1], q2 = hq[2], q3 = hq[3];
    DOT4(0, q0) q0 = hq[4];
    DOT4(1, q1) q1 = hq[5];
    DOT4(2, q2) q2 = hq[6];
    DOT4(3, q3) q3 = hq[7];
    DOT4(4, q0)
    DOT4(5, q1)
    DOT4(6, q2)
    DOT4(7, q3)

    // reduce partial sums across the 4 k-quarter lanes (quad)
    a0 += dpp_x1(a0); a1 += dpp_x1(a1); a2 += dpp_x1(a2); a3 += dpp_x1(a3);
    a0 += dpp_x2(a0); a1 += dpp_x2(a1); a2 += dpp_x2(a2); a3 += dpp_x2(a3);
    float gh = (kq == 0) ? a0 : ((kq == 1) ? a1 : ((kq == 2) ? a2 : a3));
    gh += bhh;  // thread j now owns gh for gate-row j (incl. b_hh)

    if (j < 512) {
      sbuf[j] = sigf(giv + gh);     // r (rows 0..255), z (rows 256..511)
    } else {
      sbuf[j] = gh;                 // h_n (with b_hh)
      gbuf[j - 512] = giv;          // i_n (with b_ih)
    }
    __syncthreads();

    if (j < 256) {
      float r = sbuf[j], z = sbuf[j + 256], hn = sbuf[j + 512], gin = gbuf[j];
      float n = tanhf2(gin + r * hn);
      float nh = (1.f - z) * n + z * hreg;
      float hnew = hreg * (1.f - mt) + nh * mt;
      outb[t * HH + j] = nh;        // reference outputs nh (pre-mask candidate)
      hreg = hnew;
      int wd = j >> 1;
      h16h[((wd >> 5) * 40 + (wd & 31)) * 2 + (j & 1)] = (f16)hnew;
    }
    __syncthreads();
  }

  if (j < 256) out[(size_t)BB * TT * HH + b * HH + j] = hreg;  // final state
}

extern "C" void kernel_launch(void* const* d_in, const int* in_sizes, int n_in,
                              void* d_out, int out_size, void* d_ws, size_t ws_size,
                              hipStream_t stream) {
  const float* x      = (const float*)d_in[0];
  const float* states = (const float*)d_in[1];
  const float* mask   = (const float*)d_in[2];
  const float* W_ih   = (const float*)d_in[3];
  const float* W_hh   = (const float*)d_in[4];
  const float* b_ih   = (const float*)d_in[5];
  const float* b_hh   = (const float*)d_in[6];
  float* out = (float*)d_out;

  char* ws = (char*)d_ws;
  f16* gi = (f16*)ws;
  u32* Wp = (u32*)(ws + GI_BYTES);

  prepack_whh<<<dim3(384), dim3(256), 0, stream>>>(W_hh, Wp);
  gemm_gi<<<dim3(512), dim3(256), 0, stream>>>(x, W_ih, b_ih, gi);
  recur<<<dim3(64), dim3(768), 0, stream>>>(Wp, gi, states, mask, b_hh, out);
}

// Round 3
// 1571.714 us; speedup vs baseline: 1.0662x; 1.0662x over previous
//
#include <hip/hip_runtime.h>

typedef unsigned int u32;
typedef __fp16 f16;
typedef __fp16 h2 __attribute__((ext_vector_type(2)));
typedef __fp16 h8 __attribute__((ext_vector_type(8)));
typedef float f32x2v __attribute__((ext_vector_type(2)));
typedef float f32x4v __attribute__((ext_vector_type(4)));
typedef float f32x16v __attribute__((ext_vector_type(16)));
typedef u32 u32x4v __attribute__((ext_vector_type(4)));

static constexpr int BB = 64;     // batch
static constexpr int TT = 1024;   // seq len
static constexpr int HH = 256;    // hidden
static constexpr int GG = 768;    // 3*H
static constexpr size_t GI_BYTES = (size_t)BB * TT * GG * 2;  // f16 gi buffer

__device__ __forceinline__ u32 pk2(float a, float b) {
  h2 r = __builtin_amdgcn_cvt_pkrtz(a, b);
  return __builtin_bit_cast(u32, r);
}
__device__ __forceinline__ float fdot2u(u32 a, u32 b, float c) {
  return __builtin_amdgcn_fdot2(__builtin_bit_cast(h2, a), __builtin_bit_cast(h2, b), c, false);
}
__device__ __forceinline__ float dpp_x1(float x) {  // quad_perm [1,0,3,2]
  return __builtin_bit_cast(float,
      __builtin_amdgcn_mov_dpp(__builtin_bit_cast(int, x), 0xB1, 0xF, 0xF, true));
}
__device__ __forceinline__ float dpp_x2(float x) {  // quad_perm [2,3,0,1]
  return __builtin_bit_cast(float,
      __builtin_amdgcn_mov_dpp(__builtin_bit_cast(int, x), 0x4E, 0xF, 0xF, true));
}
__device__ __forceinline__ float sigf(float x) { return 1.f / (1.f + __expf(-x)); }
__device__ __forceinline__ float tanhf2(float x) {
  float e = __expf(2.f * x);
  return 1.f - 2.f / (e + 1.f);
}

// ---------------------------------------------------------------------------
// Phase 0: prepack W_hh (768x256 fp32) into per-thread f16x2 streams.
// ---------------------------------------------------------------------------
__global__ void prepack_whh(const float* __restrict__ Whh, u32* __restrict__ Wp) {
  int id = blockIdx.x * 256 + threadIdx.x;  // [0, 128*768)
  int v = id / GG;
  int j = id - v * GG;
  int q = j >> 2, kq = j & 3;
  int row = 4 * q + (v >> 5);
  int k0 = 64 * kq + 2 * (v & 31);
  const float* p = Whh + (size_t)row * HH + k0;
  Wp[id] = pk2(p[0], p[1]);
}

// ---------------------------------------------------------------------------
// Phase 1: gi = x @ W_ih^T + b_ih, stored f16.  (unchanged this round)
// ---------------------------------------------------------------------------
__device__ __forceinline__ f32x16v zero16() {
  f32x16v z;
#pragma unroll
  for (int i = 0; i < 16; ++i) z[i] = 0.f;
  return z;
}

__global__ __launch_bounds__(256, 2) void gemm_gi(
    const float* __restrict__ x, const float* __restrict__ Wih,
    const float* __restrict__ bih, f16* __restrict__ gi) {
  __shared__ u32 bl[16384];  // 128 rows x 128 dwords (f16x2) = 64KB
  const int tid = threadIdx.x;
  const int lane = tid & 63;
  const int wv = tid >> 6;
  const int wr = wv >> 1, wc = wv & 1;
  const int l31 = lane & 31, lh = lane >> 5;
  const int m0 = blockIdx.x << 7;

  u32x4v afr[2][16];
#pragma unroll
  for (int fr = 0; fr < 2; ++fr) {
#pragma unroll
    for (int km = 0; km < 16; ++km) {
      int row = m0 + wr * 64 + fr * 32 + l31;
      int k0 = km * 16 + lh * 8;
      const f32x4v* p = (const f32x4v*)(x + (size_t)row * 256 + k0);
      f32x4v u = p[0], v = p[1];
      u32x4v t;
      t.x = pk2(u.x, u.y); t.y = pk2(u.z, u.w);
      t.z = pk2(v.x, v.y); t.w = pk2(v.z, v.w);
      afr[fr][km] = t;
    }
  }

  for (int nt = 0; nt < 6; ++nt) {
    const int n0 = nt << 7;
#pragma unroll
    for (int i = 0; i < 64; ++i) {
      int idx = i * 256 + tid;
      int r = idx >> 7, wd = idx & 127;
      const f32x2v* g = (const f32x2v*)(Wih + (size_t)(n0 + r) * 256 + 2 * wd);
      f32x2v f = *g;
      bl[r * 128 + (wd ^ ((r & 15) << 2))] = pk2(f.x, f.y);
    }
    __syncthreads();

    f32x16v acc00 = zero16(), acc01 = zero16(), acc10 = zero16(), acc11 = zero16();
#pragma unroll
    for (int km = 0; km < 16; ++km) {
      int w0 = km * 8 + lh * 4;
      int rc0 = wc * 64 + l31;
      int rc1 = wc * 64 + 32 + l31;
      u32x4v b0 = *(const u32x4v*)&bl[rc0 * 128 + (w0 ^ ((rc0 & 15) << 2))];
      u32x4v b1 = *(const u32x4v*)&bl[rc1 * 128 + (w0 ^ ((rc1 & 15) << 2))];
      h8 a0h = __builtin_bit_cast(h8, afr[0][km]);
      h8 a1h = __builtin_bit_cast(h8, afr[1][km]);
      h8 b0h = __builtin_bit_cast(h8, b0);
      h8 b1h = __builtin_bit_cast(h8, b1);
      acc00 = __builtin_amdgcn_mfma_f32_32x32x16_f16(a0h, b0h, acc00, 0, 0, 0);
      acc10 = __builtin_amdgcn_mfma_f32_32x32x16_f16(a1h, b0h, acc10, 0, 0, 0);
      acc01 = __builtin_amdgcn_mfma_f32_32x32x16_f16(a0h, b1h, acc01, 0, 0, 0);
      acc11 = __builtin_amdgcn_mfma_f32_32x32x16_f16(a1h, b1h, acc11, 0, 0, 0);
    }

#define EPI(ACC, FR, FC)                                                      \
    {                                                                         \
      int gc = n0 + wc * 64 + (FC) * 32 + l31;                                \
      float bias = bih[gc];                                                   \
      _Pragma("unroll")                                                       \
      for (int rg = 0; rg < 16; ++rg) {                                       \
        int gr = m0 + wr * 64 + (FR) * 32 + 4 * lh + (rg & 3) + 8 * (rg >> 2);\
        gi[(size_t)gr * 768 + gc] = (f16)(ACC[rg] + bias);                    \
      }                                                                       \
    }
    EPI(acc00, 0, 0) EPI(acc10, 1, 0) EPI(acc01, 0, 1) EPI(acc11, 1, 1)
#undef EPI
    __syncthreads();
  }
}

// ---------------------------------------------------------------------------
// Phase 2: the recurrence, software-pipelined.
//  - mask preloaded to LDS (removes global load from step path)
//  - gi value for step t+1 prefetched at top of step t (f16 reg, cvt at use)
//  - out store of step t's nh deferred to top of step t+1 (overlaps dot phase,
//    so the vmcnt(0) drain before each barrier is off the critical path)
// ---------------------------------------------------------------------------
#define DOT4(C, QQ)                                                   \
  a0 = fdot2u(w[(C) * 4 + 0], (QQ).x, a0);                            \
  a0 = fdot2u(w[(C) * 4 + 1], (QQ).y, a0);                            \
  a0 = fdot2u(w[(C) * 4 + 2], (QQ).z, a0);                            \
  a0 = fdot2u(w[(C) * 4 + 3], (QQ).w, a0);                            \
  a1 = fdot2u(w[32 + (C) * 4 + 0], (QQ).x, a1);                       \
  a1 = fdot2u(w[32 + (C) * 4 + 1], (QQ).y, a1);                       \
  a1 = fdot2u(w[32 + (C) * 4 + 2], (QQ).z, a1);                       \
  a1 = fdot2u(w[32 + (C) * 4 + 3], (QQ).w, a1);                       \
  a2 = fdot2u(w[64 + (C) * 4 + 0], (QQ).x, a2);                       \
  a2 = fdot2u(w[64 + (C) * 4 + 1], (QQ).y, a2);                       \
  a2 = fdot2u(w[64 + (C) * 4 + 2], (QQ).z, a2);                       \
  a2 = fdot2u(w[64 + (C) * 4 + 3], (QQ).w, a2);                       \
  a3 = fdot2u(w[96 + (C) * 4 + 0], (QQ).x, a3);                       \
  a3 = fdot2u(w[96 + (C) * 4 + 1], (QQ).y, a3);                       \
  a3 = fdot2u(w[96 + (C) * 4 + 2], (QQ).z, a3);                       \
  a3 = fdot2u(w[96 + (C) * 4 + 3], (QQ).w, a3);

__global__ __launch_bounds__(768) void recur(
    const u32* __restrict__ Wp, const f16* __restrict__ gi,
    const float* __restrict__ states, const float* __restrict__ mask,
    const float* __restrict__ bhh_g, float* __restrict__ out) {
  const int b = blockIdx.x;
  const int j = threadIdx.x;
  const int kq = j & 3;

  __shared__ u32 h16[160];    // 4 quarters of 32 dwords, padded to 40
  __shared__ float sbuf[768];
  __shared__ float gbuf[256];
  __shared__ float mlds[TT];  // whole mask row, 4 KB

  u32 w[128];
#pragma unroll
  for (int v = 0; v < 128; ++v) w[v] = Wp[(size_t)v * 768 + j];
  float bhh = bhh_g[j];

  const float* mk = mask + b * TT;
  const f16* gib = gi + (size_t)b * TT * GG;
  float* outb = out + (size_t)b * TT * HH;
  f16* h16h = (f16*)h16;

  for (int i = j; i < TT; i += 768) mlds[i] = mk[i];

  float hreg = 0.f;
  if (j < 256) {
    hreg = states[b * HH + j] * mk[0];
    int wd = j >> 1;
    h16h[((wd >> 5) * 40 + (wd & 31)) * 2 + (j & 1)] = (f16)hreg;
  }
  __syncthreads();

  const u32x4v* hq = (const u32x4v*)&h16[kq * 40];

  f16 gcur = gib[j];          // step 0's gi value
  float nh_prev = 0.f;

  for (int t = 0; t < TT; ++t) {
    // ---- issue all global traffic for this step up front ----
    int tn = (t + 1 < TT) ? (t + 1) : (TT - 1);
    f16 gnext = gib[(size_t)tn * GG + j];          // prefetch (dead on last iter)
    if (t > 0 && j < 256) outb[(size_t)(t - 1) * HH + j] = nh_prev;

    float giv = (float)gcur;
    float mt = mlds[t];

    float a0 = 0.f, a1 = 0.f, a2 = 0.f, a3 = 0.f;
    u32x4v q0 = hq[0], q1 = hq[1], q2 = hq[2], q3 = hq[3];
    DOT4(0, q0) q0 = hq[4];
    DOT4(1, q1) q1 = hq[5];
    DOT4(2, q2) q2 = hq[6];
    DOT4(3, q3) q3 = hq[7];
    DOT4(4, q0)
    DOT4(5, q1)
    DOT4(6, q2)
    DOT4(7, q3)

    a0 += dpp_x1(a0); a1 += dpp_x1(a1); a2 += dpp_x1(a2); a3 += dpp_x1(a3);
    a0 += dpp_x2(a0); a1 += dpp_x2(a1); a2 += dpp_x2(a2); a3 += dpp_x2(a3);
    float gh = (kq == 0) ? a0 : ((kq == 1) ? a1 : ((kq == 2) ? a2 : a3));
    gh += bhh;

    if (j < 512) {
      sbuf[j] = sigf(giv + gh);     // r, z
    } else {
      sbuf[j] = gh;                 // h_n partial (with b_hh)
      gbuf[j - 512] = giv;          // i_n (with b_ih)
    }
    __syncthreads();

    if (j < 256) {
      float r = sbuf[j], z = sbuf[j + 256], hn = sbuf[j + 512], gin = gbuf[j];
      float n = tanhf2(gin + r * hn);
      float nh = (1.f - z) * n + z * hreg;
      float hnew = hreg * (1.f - mt) + nh * mt;
      nh_prev = nh;                 // stored at top of next step
      hreg = hnew;
      int wd = j >> 1;
      h16h[((wd >> 5) * 40 + (wd & 31)) * 2 + (j & 1)] = (f16)hnew;
    }
    __syncthreads();
    gcur = gnext;
  }

  if (j < 256) {
    outb[(size_t)(TT - 1) * HH + j] = nh_prev;
    out[(size_t)BB * TT * HH + b * HH + j] = hreg;  // final state
  }
}

extern "C" void kernel_launch(void* const* d_in, const int* in_sizes, int n_in,
                              void* d_out, int out_size, void* d_ws, size_t ws_size,
                              hipStream_t stream) {
  const float* x      = (const float*)d_in[0];
  const float* states = (const float*)d_in[1];
  const float* mask   = (const float*)d_in[2];
  const float* W_ih   = (const float*)d_in[3];
  const float* W_hh   = (const float*)d_in[4];
  const float* b_ih   = (const float*)d_in[5];
  const float* b_hh   = (const float*)d_in[6];
  float* out = (float*)d_out;

  char* ws = (char*)d_ws;
  f16* gi = (f16*)ws;
  u32* Wp = (u32*)(ws + GI_BYTES);

  prepack_whh<<<dim3(384), dim3(256), 0, stream>>>(W_hh, Wp);
  gemm_gi<<<dim3(512), dim3(256), 0, stream>>>(x, W_ih, b_ih, gi);
  recur<<<dim3(64), dim3(768), 0, stream>>>(Wp, gi, states, mask, b_hh, out);
}

// Round 4
// 1561.038 us; speedup vs baseline: 1.0735x; 1.0068x over previous
//
#include <hip/hip_runtime.h>

typedef unsigned int u32;
typedef __fp16 f16;
typedef __fp16 h2 __attribute__((ext_vector_type(2)));
typedef __fp16 h8 __attribute__((ext_vector_type(8)));
typedef float f32x2v __attribute__((ext_vector_type(2)));
typedef float f32x4v __attribute__((ext_vector_type(4)));
typedef float f32x16v __attribute__((ext_vector_type(16)));
typedef u32 u32x4v __attribute__((ext_vector_type(4)));

static constexpr int BB = 64;     // batch
static constexpr int TT = 1024;   // seq len
static constexpr int HH = 256;    // hidden
static constexpr int GG = 768;    // 3*H
static constexpr size_t GI_BYTES = (size_t)BB * TT * GG * 2;  // f16 gi buffer

__device__ __forceinline__ u32 pk2(float a, float b) {
  h2 r = __builtin_amdgcn_cvt_pkrtz(a, b);
  return __builtin_bit_cast(u32, r);
}
__device__ __forceinline__ float fdot2u(u32 a, u32 b, float c) {
  return __builtin_amdgcn_fdot2(__builtin_bit_cast(h2, a), __builtin_bit_cast(h2, b), c, false);
}
__device__ __forceinline__ float dpp_x1(float x) {  // quad_perm [1,0,3,2]
  return __builtin_bit_cast(float,
      __builtin_amdgcn_mov_dpp(__builtin_bit_cast(int, x), 0xB1, 0xF, 0xF, true));
}
__device__ __forceinline__ float sigf(float x) { return 1.f / (1.f + __expf(-x)); }
__device__ __forceinline__ float tanhf2(float x) {
  float e = __expf(2.f * x);
  return 1.f - 2.f / (e + 1.f);
}

// ---------------------------------------------------------------------------
// Phase 0: prepack W_hh (768x256 fp32) for the pair-per-unit recur layout.
// Recur thread j (u=j>>1, kh=j&1) owns rows {u, 256+u, 512+u} over k-half
// [128*kh, 128*kh+128).  Register v = g*64+d of thread j holds
// W_hh[g*256+u][128*kh + 2d .. +1] packed f16x2.  Stored Wp[v*512 + j] so the
// one-time register fill is lane-coalesced.
// ---------------------------------------------------------------------------
__global__ void prepack_whh(const float* __restrict__ Whh, u32* __restrict__ Wp) {
  int id = blockIdx.x * 256 + threadIdx.x;  // [0, 192*512)
  int v = id >> 9;          // weight reg index [0,192)
  int j = id & 511;         // recur thread id
  int u = j >> 1, kh = j & 1;
  int g = v >> 6, d = v & 63;
  int row = g * 256 + u;
  int k0 = 128 * kh + 2 * d;
  const float* p = Whh + (size_t)row * HH + k0;
  Wp[id] = pk2(p[0], p[1]);
}

// ---------------------------------------------------------------------------
// Phase 1: gi = x @ W_ih^T + b_ih, stored f16.  (unchanged this round)
// ---------------------------------------------------------------------------
__device__ __forceinline__ f32x16v zero16() {
  f32x16v z;
#pragma unroll
  for (int i = 0; i < 16; ++i) z[i] = 0.f;
  return z;
}

__global__ __launch_bounds__(256, 2) void gemm_gi(
    const float* __restrict__ x, const float* __restrict__ Wih,
    const float* __restrict__ bih, f16* __restrict__ gi) {
  __shared__ u32 bl[16384];  // 128 rows x 128 dwords (f16x2) = 64KB
  const int tid = threadIdx.x;
  const int lane = tid & 63;
  const int wv = tid >> 6;
  const int wr = wv >> 1, wc = wv & 1;
  const int l31 = lane & 31, lh = lane >> 5;
  const int m0 = blockIdx.x << 7;

  u32x4v afr[2][16];
#pragma unroll
  for (int fr = 0; fr < 2; ++fr) {
#pragma unroll
    for (int km = 0; km < 16; ++km) {
      int row = m0 + wr * 64 + fr * 32 + l31;
      int k0 = km * 16 + lh * 8;
      const f32x4v* p = (const f32x4v*)(x + (size_t)row * 256 + k0);
      f32x4v u = p[0], v = p[1];
      u32x4v t;
      t.x = pk2(u.x, u.y); t.y = pk2(u.z, u.w);
      t.z = pk2(v.x, v.y); t.w = pk2(v.z, v.w);
      afr[fr][km] = t;
    }
  }

  for (int nt = 0; nt < 6; ++nt) {
    const int n0 = nt << 7;
#pragma unroll
    for (int i = 0; i < 64; ++i) {
      int idx = i * 256 + tid;
      int r = idx >> 7, wd = idx & 127;
      const f32x2v* g = (const f32x2v*)(Wih + (size_t)(n0 + r) * 256 + 2 * wd);
      f32x2v f = *g;
      bl[r * 128 + (wd ^ ((r & 15) << 2))] = pk2(f.x, f.y);
    }
    __syncthreads();

    f32x16v acc00 = zero16(), acc01 = zero16(), acc10 = zero16(), acc11 = zero16();
#pragma unroll
    for (int km = 0; km < 16; ++km) {
      int w0 = km * 8 + lh * 4;
      int rc0 = wc * 64 + l31;
      int rc1 = wc * 64 + 32 + l31;
      u32x4v b0 = *(const u32x4v*)&bl[rc0 * 128 + (w0 ^ ((rc0 & 15) << 2))];
      u32x4v b1 = *(const u32x4v*)&bl[rc1 * 128 + (w0 ^ ((rc1 & 15) << 2))];
      h8 a0h = __builtin_bit_cast(h8, afr[0][km]);
      h8 a1h = __builtin_bit_cast(h8, afr[1][km]);
      h8 b0h = __builtin_bit_cast(h8, b0);
      h8 b1h = __builtin_bit_cast(h8, b1);
      acc00 = __builtin_amdgcn_mfma_f32_32x32x16_f16(a0h, b0h, acc00, 0, 0, 0);
      acc10 = __builtin_amdgcn_mfma_f32_32x32x16_f16(a1h, b0h, acc10, 0, 0, 0);
      acc01 = __builtin_amdgcn_mfma_f32_32x32x16_f16(a0h, b1h, acc01, 0, 0, 0);
      acc11 = __builtin_amdgcn_mfma_f32_32x32x16_f16(a1h, b1h, acc11, 0, 0, 0);
    }

#define EPI(ACC, FR, FC)                                                      \
    {                                                                         \
      int gc = n0 + wc * 64 + (FC) * 32 + l31;                                \
      float bias = bih[gc];                                                   \
      _Pragma("unroll")                                                       \
      for (int rg = 0; rg < 16; ++rg) {                                       \
        int gr = m0 + wr * 64 + (FR) * 32 + 4 * lh + (rg & 3) + 8 * (rg >> 2);\
        gi[(size_t)gr * 768 + gc] = (f16)(ACC[rg] + bias);                    \
      }                                                                       \
    }
    EPI(acc00, 0, 0) EPI(acc10, 1, 0) EPI(acc01, 0, 1) EPI(acc11, 1, 1)
#undef EPI
    __syncthreads();
  }
}

// ---------------------------------------------------------------------------
// Phase 2: recurrence, pair-per-unit layout.
// 64 blocks x 512 threads (8 waves, 2/SIMD). Lane pair (2u,2u+1) owns hidden
// unit u: all 3 gate rows, k split in halves across the pair (192 weight
// dwords in VGPRs). No gate exchange: one dpp pair-reduce completes each gh.
// h double-buffered in LDS -> ONE barrier per step. Gate math on all lanes
// (redundant per pair, zero divergence). gi prefetched 1 step ahead; out
// store deferred 1 step.
// ---------------------------------------------------------------------------
__global__ __launch_bounds__(512, 2) void recur(
    const u32* __restrict__ Wp, const f16* __restrict__ gi,
    const float* __restrict__ states, const float* __restrict__ mask,
    const float* __restrict__ bhh_g, float* __restrict__ out) {
  const int b = blockIdx.x;
  const int j = threadIdx.x;
  const int u = j >> 1;
  const int kh = j & 1;

  __shared__ u32 hbuf[2][128];   // 256 f16 each
  __shared__ float mlds[TT];     // mask row, 4 KB

  u32 w[192];
#pragma unroll
  for (int v = 0; v < 192; ++v) w[v] = Wp[(size_t)v * 512 + j];

  const float bhr = bhh_g[u];
  const float bhz = bhh_g[256 + u];
  const float bhn = bhh_g[512 + u];

  const float* mk = mask + b * TT;
  const f16* gib = gi + (size_t)b * TT * GG;
  float* outb = out + (size_t)b * TT * HH;

  for (int i = j; i < TT; i += 512) mlds[i] = mk[i];

  float hreg = states[b * HH + u] * mk[0];   // both lanes of the pair
  if (kh == 0) ((f16*)hbuf[0])[u] = (f16)hreg;
  __syncthreads();

  f16 gr_c = gib[u], gz_c = gib[256 + u], gn_c = gib[512 + u];
  float nh_prev = 0.f;

#pragma unroll 2
  for (int t = 0; t < TT; ++t) {
    // ---- issue next step's global traffic up front ----
    int tn = (t + 1 < TT) ? (t + 1) : (TT - 1);
    const f16* gnp = gib + (size_t)tn * GG;
    f16 gr_n = gnp[u], gz_n = gnp[256 + u], gn_n = gnp[512 + u];
    if (t > 0 && kh == 0) outb[(size_t)(t - 1) * HH + u] = nh_prev;

    const float mt = mlds[t];
    const u32x4v* hq = (const u32x4v*)&hbuf[t & 1][kh << 6];

    float ar0 = 0.f, ar1 = 0.f, az0 = 0.f, az1 = 0.f, an0 = 0.f, an1 = 0.f;
#pragma unroll
    for (int gp = 0; gp < 4; ++gp) {
      u32x4v q0 = hq[gp * 4 + 0], q1 = hq[gp * 4 + 1];
      u32x4v q2 = hq[gp * 4 + 2], q3 = hq[gp * 4 + 3];
      const u32* qq = (const u32*)&q0;  // q0..q3 contiguous? no — index explicitly
      u32 qa[16] = {q0.x, q0.y, q0.z, q0.w, q1.x, q1.y, q1.z, q1.w,
                    q2.x, q2.y, q2.z, q2.w, q3.x, q3.y, q3.z, q3.w};
      (void)qq;
#pragma unroll
      for (int d = 0; d < 16; ++d) {
        int v = gp * 16 + d;
        if (d & 1) {
          ar1 = fdot2u(w[v], qa[d], ar1);
          az1 = fdot2u(w[64 + v], qa[d], az1);
          an1 = fdot2u(w[128 + v], qa[d], an1);
        } else {
          ar0 = fdot2u(w[v], qa[d], ar0);
          az0 = fdot2u(w[64 + v], qa[d], az0);
          an0 = fdot2u(w[128 + v], qa[d], an0);
        }
      }
    }
    float ghr = ar0 + ar1, ghz = az0 + az1, ghn = an0 + an1;
    // pair-reduce across the two k-halves (lane 2u <-> 2u+1)
    ghr += dpp_x1(ghr); ghz += dpp_x1(ghz); ghn += dpp_x1(ghn);
    ghr += bhr; ghz += bhz; ghn += bhn;

    float r = sigf((float)gr_c + ghr);
    float z = sigf((float)gz_c + ghz);
    float n = tanhf2((float)gn_c + r * ghn);
    float nh = (1.f - z) * n + z * hreg;
    float hnew = hreg * (1.f - mt) + nh * mt;
    nh_prev = nh;
    hreg = hnew;
    if (kh == 0) ((f16*)hbuf[(t + 1) & 1])[u] = (f16)hnew;
    gr_c = gr_n; gz_c = gz_n; gn_c = gn_n;
    __syncthreads();
  }

  if (kh == 0) {
    outb[(size_t)(TT - 1) * HH + u] = nh_prev;
    out[(size_t)BB * TT * HH + b * HH + u] = hreg;  // final state
  }
}

extern "C" void kernel_launch(void* const* d_in, const int* in_sizes, int n_in,
                              void* d_out, int out_size, void* d_ws, size_t ws_size,
                              hipStream_t stream) {
  const float* x      = (const float*)d_in[0];
  const float* states = (const float*)d_in[1];
  const float* mask   = (const float*)d_in[2];
  const float* W_ih   = (const float*)d_in[3];
  const float* W_hh   = (const float*)d_in[4];
  const float* b_ih   = (const float*)d_in[5];
  const float* b_hh   = (const float*)d_in[6];
  float* out = (float*)d_out;

  char* ws = (char*)d_ws;
  f16* gi = (f16*)ws;
  u32* Wp = (u32*)(ws + GI_BYTES);

  prepack_whh<<<dim3(384), dim3(256), 0, stream>>>(W_hh, Wp);
  gemm_gi<<<dim3(512), dim3(256), 0, stream>>>(x, W_ih, b_ih, gi);
  recur<<<dim3(64), dim3(512), 0, stream>>>(Wp, gi, states, mask, b_hh, out);
}

// Round 5
// 1541.238 us; speedup vs baseline: 1.0873x; 1.0128x over previous
//
#include <hip/hip_runtime.h>

typedef unsigned int u32;
typedef __fp16 f16;
typedef __fp16 h2 __attribute__((ext_vector_type(2)));
typedef __fp16 h8 __attribute__((ext_vector_type(8)));
typedef float f32x2v __attribute__((ext_vector_type(2)));
typedef float f32x4v __attribute__((ext_vector_type(4)));
typedef float f32x16v __attribute__((ext_vector_type(16)));
typedef u32 u32x4v __attribute__((ext_vector_type(4)));

static constexpr int BB = 64;     // batch
static constexpr int TT = 1024;   // seq len
static constexpr int HH = 256;    // hidden
static constexpr int GG = 768;    // 3*H
static constexpr size_t GI_BYTES = (size_t)BB * TT * GG * 2;  // f16 gi buffer

__device__ __forceinline__ u32 pk2(float a, float b) {
  h2 r = __builtin_amdgcn_cvt_pkrtz(a, b);
  return __builtin_bit_cast(u32, r);
}
__device__ __forceinline__ float fdot2u(u32 a, u32 b, float c) {
  return __builtin_amdgcn_fdot2(__builtin_bit_cast(h2, a), __builtin_bit_cast(h2, b), c, false);
}
__device__ __forceinline__ float dpp_x1(float x) {  // quad_perm [1,0,3,2]
  return __builtin_bit_cast(float,
      __builtin_amdgcn_mov_dpp(__builtin_bit_cast(int, x), 0xB1, 0xF, 0xF, true));
}
__device__ __forceinline__ float sigf(float x) { return 1.f / (1.f + __expf(-x)); }
__device__ __forceinline__ float tanhf2(float x) {
  float e = __expf(2.f * x);
  return 1.f - 2.f / (e + 1.f);
}

// ---------------------------------------------------------------------------
// Phase 0: prepack W_hh (768x256 fp32) for the pair-per-unit recur layout.
// Recur thread j (u=j>>1, kh=j&1) owns rows {u, 256+u, 512+u} over k-half
// [128*kh, 128*kh+128).  Register v = g*64+d of thread j holds
// W_hh[g*256+u][128*kh + 2d .. +1] packed f16x2.  Stored Wp[v*512 + j].
// ---------------------------------------------------------------------------
__global__ void prepack_whh(const float* __restrict__ Whh, u32* __restrict__ Wp) {
  int id = blockIdx.x * 256 + threadIdx.x;  // [0, 192*512)
  int v = id >> 9;          // weight reg index [0,192)
  int j = id & 511;         // recur thread id
  int u = j >> 1, kh = j & 1;
  int g = v >> 6, d = v & 63;
  int row = g * 256 + u;
  int k0 = 128 * kh + 2 * d;
  const float* p = Whh + (size_t)row * HH + k0;
  Wp[id] = pk2(p[0], p[1]);
}

// ---------------------------------------------------------------------------
// Phase 1: gi = x @ W_ih^T + b_ih, stored f16.  (unchanged this round)
// ---------------------------------------------------------------------------
__device__ __forceinline__ f32x16v zero16() {
  f32x16v z;
#pragma unroll
  for (int i = 0; i < 16; ++i) z[i] = 0.f;
  return z;
}

__global__ __launch_bounds__(256, 2) void gemm_gi(
    const float* __restrict__ x, const float* __restrict__ Wih,
    const float* __restrict__ bih, f16* __restrict__ gi) {
  __shared__ u32 bl[16384];  // 128 rows x 128 dwords (f16x2) = 64KB
  const int tid = threadIdx.x;
  const int lane = tid & 63;
  const int wv = tid >> 6;
  const int wr = wv >> 1, wc = wv & 1;
  const int l31 = lane & 31, lh = lane >> 5;
  const int m0 = blockIdx.x << 7;

  u32x4v afr[2][16];
#pragma unroll
  for (int fr = 0; fr < 2; ++fr) {
#pragma unroll
    for (int km = 0; km < 16; ++km) {
      int row = m0 + wr * 64 + fr * 32 + l31;
      int k0 = km * 16 + lh * 8;
      const f32x4v* p = (const f32x4v*)(x + (size_t)row * 256 + k0);
      f32x4v u = p[0], v = p[1];
      u32x4v t;
      t.x = pk2(u.x, u.y); t.y = pk2(u.z, u.w);
      t.z = pk2(v.x, v.y); t.w = pk2(v.z, v.w);
      afr[fr][km] = t;
    }
  }

  for (int nt = 0; nt < 6; ++nt) {
    const int n0 = nt << 7;
#pragma unroll
    for (int i = 0; i < 64; ++i) {
      int idx = i * 256 + tid;
      int r = idx >> 7, wd = idx & 127;
      const f32x2v* g = (const f32x2v*)(Wih + (size_t)(n0 + r) * 256 + 2 * wd);
      f32x2v f = *g;
      bl[r * 128 + (wd ^ ((r & 15) << 2))] = pk2(f.x, f.y);
    }
    __syncthreads();

    f32x16v acc00 = zero16(), acc01 = zero16(), acc10 = zero16(), acc11 = zero16();
#pragma unroll
    for (int km = 0; km < 16; ++km) {
      int w0 = km * 8 + lh * 4;
      int rc0 = wc * 64 + l31;
      int rc1 = wc * 64 + 32 + l31;
      u32x4v b0 = *(const u32x4v*)&bl[rc0 * 128 + (w0 ^ ((rc0 & 15) << 2))];
      u32x4v b1 = *(const u32x4v*)&bl[rc1 * 128 + (w0 ^ ((rc1 & 15) << 2))];
      h8 a0h = __builtin_bit_cast(h8, afr[0][km]);
      h8 a1h = __builtin_bit_cast(h8, afr[1][km]);
      h8 b0h = __builtin_bit_cast(h8, b0);
      h8 b1h = __builtin_bit_cast(h8, b1);
      acc00 = __builtin_amdgcn_mfma_f32_32x32x16_f16(a0h, b0h, acc00, 0, 0, 0);
      acc10 = __builtin_amdgcn_mfma_f32_32x32x16_f16(a1h, b0h, acc10, 0, 0, 0);
      acc01 = __builtin_amdgcn_mfma_f32_32x32x16_f16(a0h, b1h, acc01, 0, 0, 0);
      acc11 = __builtin_amdgcn_mfma_f32_32x32x16_f16(a1h, b1h, acc11, 0, 0, 0);
    }

#define EPI(ACC, FR, FC)                                                      \
    {                                                                         \
      int gc = n0 + wc * 64 + (FC) * 32 + l31;                                \
      float bias = bih[gc];                                                   \
      _Pragma("unroll")                                                       \
      for (int rg = 0; rg < 16; ++rg) {                                       \
        int gr = m0 + wr * 64 + (FR) * 32 + 4 * lh + (rg & 3) + 8 * (rg >> 2);\
        gi[(size_t)gr * 768 + gc] = (f16)(ACC[rg] + bias);                    \
      }                                                                       \
    }
    EPI(acc00, 0, 0) EPI(acc10, 1, 0) EPI(acc01, 0, 1) EPI(acc11, 1, 1)
#undef EPI
    __syncthreads();
  }
}

// ---------------------------------------------------------------------------
// Phase 2: recurrence, pair-per-unit layout, weights PINNED in VGPRs.
// 64 blocks x 512 threads (8 waves, 2/SIMD, VGPR cap 256). Lane pair
// (2u,2u+1) owns hidden unit u: 3 gate rows, k split in halves across the
// pair (192 weight dwords in VGPRs, held via opaque asm pin so the compiler
// cannot rematerialize the loads inside the t-loop). One barrier per step.
// ---------------------------------------------------------------------------
__global__ __launch_bounds__(512, 2) void recur(
    const u32* __restrict__ Wp, const f16* __restrict__ gi,
    const float* __restrict__ states, const float* __restrict__ mask,
    const float* __restrict__ bhh_g, float* __restrict__ out) {
  const int b = blockIdx.x;
  const int j = threadIdx.x;
  const int u = j >> 1;
  const int kh = j & 1;

  __shared__ u32 hbuf[2][128];   // 256 f16 each
  __shared__ float mlds[TT];     // mask row, 4 KB

  u32 w[192];
#pragma unroll
  for (int v = 0; v < 192; ++v) w[v] = Wp[(size_t)v * 512 + j];
  // Opaque pin: forces each weight into a live VGPR; the volatile asm cannot
  // be duplicated or sunk into the loop, so loads are not rematerialized.
#pragma unroll
  for (int v = 0; v < 192; ++v) asm volatile("" : "+v"(w[v]));

  const float bhr = bhh_g[u];
  const float bhz = bhh_g[256 + u];
  const float bhn = bhh_g[512 + u];

  const float* mk = mask + b * TT;
  const f16* gib = gi + (size_t)b * TT * GG;
  float* outb = out + (size_t)b * TT * HH;

  for (int i = j; i < TT; i += 512) mlds[i] = mk[i];

  float hreg = states[b * HH + u] * mk[0];   // both lanes of the pair
  if (kh == 0) ((f16*)hbuf[0])[u] = (f16)hreg;
  __syncthreads();

  f16 gr_c = gib[u], gz_c = gib[256 + u], gn_c = gib[512 + u];
  float nh_prev = 0.f;

  for (int t = 0; t < TT; ++t) {
    // ---- issue next step's global traffic up front ----
    int tn = (t + 1 < TT) ? (t + 1) : (TT - 1);
    const f16* gnp = gib + (size_t)tn * GG;
    f16 gr_n = gnp[u], gz_n = gnp[256 + u], gn_n = gnp[512 + u];
    if (t > 0 && kh == 0) outb[(size_t)(t - 1) * HH + u] = nh_prev;

    const float mt = mlds[t];
    const u32x4v* hq = (const u32x4v*)&hbuf[t & 1][kh << 6];

    float ar0 = 0.f, ar1 = 0.f, az0 = 0.f, az1 = 0.f, an0 = 0.f, an1 = 0.f;
#pragma unroll
    for (int gp = 0; gp < 16; ++gp) {
      u32x4v q = hq[gp];
      const int v = gp * 4;
      ar0 = fdot2u(w[v + 0], q.x, ar0);
      az0 = fdot2u(w[64 + v + 0], q.x, az0);
      an0 = fdot2u(w[128 + v + 0], q.x, an0);
      ar1 = fdot2u(w[v + 1], q.y, ar1);
      az1 = fdot2u(w[64 + v + 1], q.y, az1);
      an1 = fdot2u(w[128 + v + 1], q.y, an1);
      ar0 = fdot2u(w[v + 2], q.z, ar0);
      az0 = fdot2u(w[64 + v + 2], q.z, az0);
      an0 = fdot2u(w[128 + v + 2], q.z, an0);
      ar1 = fdot2u(w[v + 3], q.w, ar1);
      az1 = fdot2u(w[64 + v + 3], q.w, az1);
      an1 = fdot2u(w[128 + v + 3], q.w, an1);
    }
    float ghr = ar0 + ar1, ghz = az0 + az1, ghn = an0 + an1;
    // pair-reduce across the two k-halves (lane 2u <-> 2u+1)
    ghr += dpp_x1(ghr); ghz += dpp_x1(ghz); ghn += dpp_x1(ghn);
    ghr += bhr; ghz += bhz; ghn += bhn;

    float r = sigf((float)gr_c + ghr);
    float z = sigf((float)gz_c + ghz);
    float n = tanhf2((float)gn_c + r * ghn);
    float nh = (1.f - z) * n + z * hreg;
    float hnew = hreg * (1.f - mt) + nh * mt;
    nh_prev = nh;
    hreg = hnew;
    if (kh == 0) ((f16*)hbuf[(t + 1) & 1])[u] = (f16)hnew;
    gr_c = gr_n; gz_c = gz_n; gn_c = gn_n;
    __syncthreads();
  }

  if (kh == 0) {
    outb[(size_t)(TT - 1) * HH + u] = nh_prev;
    out[(size_t)BB * TT * HH + b * HH + u] = hreg;  // final state
  }
}

extern "C" void kernel_launch(void* const* d_in, const int* in_sizes, int n_in,
                              void* d_out, int out_size, void* d_ws, size_t ws_size,
                              hipStream_t stream) {
  const float* x      = (const float*)d_in[0];
  const float* states = (const float*)d_in[1];
  const float* mask   = (const float*)d_in[2];
  const float* W_ih   = (const float*)d_in[3];
  const float* W_hh   = (const float*)d_in[4];
  const float* b_ih   = (const float*)d_in[5];
  const float* b_hh   = (const float*)d_in[6];
  float* out = (float*)d_out;

  char* ws = (char*)d_ws;
  f16* gi = (f16*)ws;
  u32* Wp = (u32*)(ws + GI_BYTES);

  prepack_whh<<<dim3(384), dim3(256), 0, stream>>>(W_hh, Wp);
  gemm_gi<<<dim3(512), dim3(256), 0, stream>>>(x, W_ih, b_ih, gi);
  recur<<<dim3(64), dim3(512), 0, stream>>>(Wp, gi, states, mask, b_hh, out);
}